// Round 12
// baseline (743.827 us; speedup 1.0000x reference)
//
#include <hip/hip_runtime.h>
#include <hip/hip_bf16.h>

#define S_TOK 8192
#define DM    2048
#define DFF   8192
#define NE    8
#define CAP   1024

typedef __bf16 bf16_t;
typedef __bf16 bf16x8 __attribute__((ext_vector_type(8)));
typedef float  f32x4  __attribute__((ext_vector_type(4)));

__device__ __forceinline__ void load_lds16(const void* g, void* l) {
    __builtin_amdgcn_global_load_lds((const __attribute__((address_space(1))) void*)g,
                                     (__attribute__((address_space(3))) void*)l,
                                     16, 0, 0);
}

// ---------------- Kernel 1: gate logits + argmax — one wave per token ---------------
__global__ __launch_bounds__(256) void gate_argmax(const float* __restrict__ x,
                                                   const float* __restrict__ wg,
                                                   int* __restrict__ eidx) {
    int lane = threadIdx.x & 63, wv = threadIdx.x >> 6;
    int s = blockIdx.x * 4 + wv;
    const float* row = x + (size_t)s * DM;
    float acc[8] = {0.f,0.f,0.f,0.f,0.f,0.f,0.f,0.f};
    for (int kb = 0; kb < DM; kb += 256) {
        int k0 = kb + lane * 4;
        float4 xv = *(const float4*)(row + k0);
        const float* wr = wg + (size_t)k0 * NE;
        float xs[4] = {xv.x, xv.y, xv.z, xv.w};
#pragma unroll
        for (int c = 0; c < 4; ++c) {
            float4 w0 = *(const float4*)(wr + c * 8);
            float4 w1 = *(const float4*)(wr + c * 8 + 4);
            acc[0] += xs[c] * w0.x; acc[1] += xs[c] * w0.y;
            acc[2] += xs[c] * w0.z; acc[3] += xs[c] * w0.w;
            acc[4] += xs[c] * w1.x; acc[5] += xs[c] * w1.y;
            acc[6] += xs[c] * w1.z; acc[7] += xs[c] * w1.w;
        }
    }
#pragma unroll
    for (int off = 32; off > 0; off >>= 1)
#pragma unroll
        for (int e = 0; e < 8; ++e) acc[e] += __shfl_xor(acc[e], off, 64);
    if (lane == 0) {
        float best = acc[0]; int bi = 0;
#pragma unroll
        for (int e = 1; e < 8; ++e) if (acc[e] > best) { best = acc[e]; bi = e; }
        eidx[s] = bi;
    }
}

// ---------------- Kernel 2: slot assignment — single wave, prefetch-pipelined -------
__global__ __launch_bounds__(64) void scatter_slots(const int* __restrict__ eidx,
                                                    int* __restrict__ srcOf) {
    int lane = threadIdx.x;
    unsigned long long below = (lane == 0) ? 0ull : ((1ull << lane) - 1ull);
    for (int i = lane; i < NE * CAP; i += 64) srcOf[i] = -1;

    int cnt[NE] = {0,0,0,0,0,0,0,0};
    int e_cur = eidx[lane];
    for (int it = 0; it < S_TOK / 64; ++it) {
        int e_nxt = (it < S_TOK / 64 - 1) ? eidx[(it + 1) * 64 + lane] : 0;
        int s = it * 64 + lane;
#pragma unroll
        for (int ex = 0; ex < NE; ++ex) {
            unsigned long long m = __ballot(e_cur == ex);
            if (e_cur == ex) {
                int loc = cnt[ex] + __popcll(m & below);
                if (loc < CAP) srcOf[ex * CAP + loc] = s;
            }
            cnt[ex] += __popcll(m);
        }
        e_cur = e_nxt;
    }
}

// ---------------- Kernel 3: gather + f32->bf16, 128-row pre-swizzled A images -------
// A image per (e, mt 0..7, kt 0..31): 16 KB = [128 m][64 k] bf16, row 128 B,
// 16B chunk kg at byte m*128 + ((kg ^ (m&7))<<4).  gload_lds copies linearly.
__global__ __launch_bounds__(256) void pack_rows(const float* __restrict__ x,
                                                 const int* __restrict__ srcOf,
                                                 char* __restrict__ abuf) {
    int slot = blockIdx.x;               // e*1024 + c
    int e = slot >> 10, c = slot & 1023;
    int mt = c >> 7, m = c & 127;
    int src = srcOf[slot];
    int tid = threadIdx.x;
    int kt = tid >> 3, kg = tid & 7;     // kt 0..31, kg 0..7
    bf16x8 v = {};
    if (src >= 0) {
        const float4* p = (const float4*)(x + (size_t)src * DM + kt * 64 + kg * 8);
        float4 a = p[0], b = p[1];
        v = bf16x8{(bf16_t)a.x,(bf16_t)a.y,(bf16_t)a.z,(bf16_t)a.w,
                   (bf16_t)b.x,(bf16_t)b.y,(bf16_t)b.z,(bf16_t)b.w};
    }
    size_t img = (size_t)((e * 8 + mt) * 32 + kt) * 16384;
    int off = m * 128 + ((kg ^ (m & 7)) << 4);
    *(bf16x8*)(abuf + img + off) = v;
}

// ---- Kernel 4: 128x256x64 GEMM, 256 thr / 4 waves, 48KB LDS -> 2 blocks/CU ---------
// Two co-resident blocks interleave LDS and MFMA bursts (the m114 overlap).
// LDS: A 16K @0 | B 32K @16384. B rows 128B; chunk q at (q ^ (n&7))*16.
__global__ __launch_bounds__(256, 2) void moe_gemm(const char* __restrict__ abuf,
                                                   const float* __restrict__ we,
                                                   const float* __restrict__ be,
                                                   float* __restrict__ out) {
    __shared__ uint4 smem4[49152 / 16];
    char* smem = (char*)smem4;

    int bid = blockIdx.x;
    int e  = bid & 7;                   // expert == XCD
    int r  = bid >> 3;
    int mt = r & 7;                     // 8 m-tiles of 128
    int nt = r >> 3;                    // 32 n-tiles of 256
    int tid = threadIdx.x, lane = tid & 63, wv = tid >> 6;
    int wm = wv >> 1, wn = wv & 1;      // 2x2 wave grid -> 64x128 per wave
    int lr = lane & 15, g = lane >> 4;

    const char* aI = abuf + (size_t)((e * 8 + mt) * 32) * 16384;
    // B staging: thread owns k-octet (h*4 + oct) x n-quad nq (oct=tid&3, nq=tid>>2)
    int oct = tid & 3, nq = tid >> 2;   // nq 0..63
    const float* bBase = we + (size_t)e * DM * DFF + (size_t)nt * 256 + nq * 4;

    f32x4 acc[4][8] = {};
    float4 bs0[8], bs1[8];

    auto issueB0 = [&](int kt) {
        const float* bp = bBase + ((size_t)kt * 64 + oct * 8) * DFF;
#pragma unroll
        for (int j = 0; j < 8; ++j) bs0[j] = *(const float4*)(bp + (size_t)j * DFF);
    };
    auto issueB1 = [&](int kt) {
        const float* bp = bBase + ((size_t)kt * 64 + 32 + oct * 8) * DFF;
#pragma unroll
        for (int j = 0; j < 8; ++j) bs1[j] = *(const float4*)(bp + (size_t)j * DFF);
    };
    auto writeB = [&](const float4* bsv, int h) {
        int q = h * 4 + oct;
#pragma unroll
        for (int i = 0; i < 4; ++i) {
            int n = nq * 4 + i;
            bf16x8 w;
#pragma unroll
            for (int j = 0; j < 8; ++j) {
                float v = (i == 0) ? bsv[j].x : (i == 1) ? bsv[j].y
                        : (i == 2) ? bsv[j].z : bsv[j].w;
                w[j] = (bf16_t)v;
            }
            *(bf16x8*)(smem + 16384 + n * 128 + ((q ^ (n & 7)) << 4)) = w;
        }
    };
    auto stageA = [&](int kt) {
        const char* src = aI + (size_t)kt * 16384 + tid * 16;
        char* dst = smem + tid * 16;
#pragma unroll
        for (int i = 0; i < 4; ++i) load_lds16(src + i * 4096, dst + i * 4096);
    };

    // prologue: tile 0
    issueB0(0);
    issueB1(0);
    stageA(0);
    writeB(bs0, 0);                      // compiler inserts counted waits on bs loads
    writeB(bs1, 1);
    __syncthreads();

    for (int kt = 0; kt < 32; ++kt) {
        bool nl = (kt < 31);
        if (nl) issueB0(kt + 1);         // h0 prefetch: whole compute phase to land
        __builtin_amdgcn_sched_barrier(0);

        // ---- compute tile kt ----
        bf16x8 af[4][2];
#pragma unroll
        for (int mf = 0; mf < 4; ++mf) {
            int m = wm * 64 + mf * 16 + lr;
#pragma unroll
            for (int kk = 0; kk < 2; ++kk)
                af[mf][kk] = *(const bf16x8*)(smem + m * 128 + (((kk * 4 + g) ^ (m & 7)) << 4));
        }
#pragma unroll
        for (int nf = 0; nf < 8; ++nf) {
            int n = wn * 128 + nf * 16 + lr;
            bf16x8 bfr[2];
#pragma unroll
            for (int kk = 0; kk < 2; ++kk)
                bfr[kk] = *(const bf16x8*)(smem + 16384 + n * 128 + (((kk * 4 + g) ^ (n & 7)) << 4));
            __builtin_amdgcn_s_setprio(1);
#pragma unroll
            for (int mf = 0; mf < 4; ++mf)
#pragma unroll
                for (int kk = 0; kk < 2; ++kk)
                    acc[mf][nf] = __builtin_amdgcn_mfma_f32_16x16x32_bf16(
                        af[mf][kk], bfr[kk], acc[mf][nf], 0, 0, 0);
            __builtin_amdgcn_s_setprio(0);
            if (nf == 3 && nl) issueB1(kt + 1);   // h1 prefetch mid-compute
        }

        __syncthreads();                 // all waves done reading tile kt
        if (nl) {
            stageA(kt + 1);              // gload_lds direct
            writeB(bs0, 0);              // counted waits retire bs0/bs1
            writeB(bs1, 1);
        }
        __syncthreads();                 // tile kt+1 staged & visible
    }

    // epilogue: C/D layout col=lane&15, row=(lane>>4)*4+q
    int orow0 = e * CAP + mt * 128 + wm * 64 + g * 4;
    int ocol0 = nt * 256 + wn * 128 + lr;
#pragma unroll
    for (int nf = 0; nf < 8; ++nf) {
        int oc = ocol0 + nf * 16;
        float bias = be[(size_t)e * DFF + oc];
#pragma unroll
        for (int mf = 0; mf < 4; ++mf) {
            int orow = orow0 + mf * 16;
#pragma unroll
            for (int qq = 0; qq < 4; ++qq)
                out[(size_t)(orow + qq) * DFF + oc] = acc[mf][nf][qq] + bias;
        }
    }
}

// ---------------- launcher ----------------------------------------------------------
extern "C" void kernel_launch(void* const* d_in, const int* in_sizes, int n_in,
                              void* d_out, int out_size, void* d_ws, size_t ws_size,
                              hipStream_t stream) {
    const float* x  = (const float*)d_in[0];
    const float* wg = (const float*)d_in[1];
    const float* we = (const float*)d_in[2];
    const float* be = (const float*)d_in[3];
    float* out = (float*)d_out;

    size_t need = 65536 + (size_t)32 * 1048576;   // 64 KB meta + 32 MB abuf
    if (ws_size < need) return;

    int* eidx  = (int*)d_ws;
    int* srcOf = eidx + S_TOK;
    char* abuf = (char*)d_ws + 65536;

    gate_argmax<<<S_TOK / 4, 256, 0, stream>>>(x, wg, eidx);
    scatter_slots<<<1, 64, 0, stream>>>(eidx, srcOf);
    pack_rows<<<S_TOK, 256, 0, stream>>>(x, srcOf, abuf);
    moe_gemm<<<NE * 8 * 32, 256, 0, stream>>>(abuf, we, be, out);
}